// Round 18
// baseline (1745.173 us; speedup 1.0000x reference)
//
#include <hip/hip_runtime.h>
#include <math.h>

#define Bq 512
#define Tq 128
#define Fq 64
#define Uq 1024
#define OSTEPS 24
#define NKC_W 68
#define NKC_D 64
#define SLOT ((size_t)Bq * Uq)   // f16 elements per h slot

typedef _Float16 f16x8 __attribute__((ext_vector_type(8)));
typedef _Float16 f16x2 __attribute__((ext_vector_type(2)));
typedef float f32x16 __attribute__((ext_vector_type(16)));
typedef float f32x4 __attribute__((ext_vector_type(4)));
typedef float f32x2 __attribute__((ext_vector_type(2)));

__device__ __forceinline__ float sigmoidf_(float x) {
    return 1.0f / (1.0f + __expf(-x));
}
__device__ __forceinline__ float tanhf_(float x) {
    return 2.0f / (1.0f + __expf(-2.0f * x)) - 1.0f;
}

#define BAR() do {                                             \
    asm volatile("s_waitcnt lgkmcnt(0)" ::: "memory");         \
    __builtin_amdgcn_s_barrier();                              \
} while (0)

// ---------------------------------------------------------------------------
// Pack Wh [1024][4096] + Wx [64][4096] into warmup B-frags (K=1088, 68 kc16).
// (r13/r16/r17-verified)
// ---------------------------------------------------------------------------
__global__ __launch_bounds__(256)
void pack_w(const float* __restrict__ Wh, const float* __restrict__ Wx,
            f16x8* __restrict__ BpH)
{
    long id = (long)blockIdx.x * 256 + threadIdx.x;   // 128*68*64 slots
    int lane = (int)(id & 63);
    long rest = id >> 6;
    int kc16 = (int)(rest % NKC_W);
    int gcol = (int)(rest / NKC_W);                   // 0..127
    int col = (gcol >> 5) * Uq + (gcol & 31) * 32 + (lane & 31);
    int k0 = kc16 * 16 + (lane >> 5) * 8;
    f16x8 hv;
#pragma unroll
    for (int j = 0; j < 8; ++j) {
        int k = k0 + j;
        float v = (k < Uq) ? Wh[(size_t)k * (4 * Uq) + col]
                           : Wx[(size_t)(k - Uq) * (4 * Uq) + col];
        hv[j] = (_Float16)v;
    }
    BpH[id] = hv;
}

// ---------------------------------------------------------------------------
// Wcomb = Wh + Wd @ Wx  (fp32). (r17-verified)
// ---------------------------------------------------------------------------
__global__ __launch_bounds__(256)
void wcomb_kernel(const float* __restrict__ Wh, const float* __restrict__ Wd,
                  const float* __restrict__ Wx, float* __restrict__ Wtmp)
{
    __shared__ float WdL[8][64];
    const int tid = threadIdx.x;
    const int kb = (int)blockIdx.x >> 4;     // 0..127
    const int cb = (int)blockIdx.x & 15;
    const int k0 = kb * 8;
    const int col = cb * 256 + tid;
    {
        int i0 = tid, i1 = tid + 256;
        WdL[i0 >> 6][i0 & 63] = Wd[(size_t)(k0 + (i0 >> 6)) * Fq + (i0 & 63)];
        WdL[i1 >> 6][i1 & 63] = Wd[(size_t)(k0 + (i1 >> 6)) * Fq + (i1 & 63)];
    }
    __syncthreads();
    float acc[8];
#pragma unroll
    for (int kk = 0; kk < 8; ++kk)
        acc[kk] = Wh[(size_t)(k0 + kk) * (4 * Uq) + col];
    for (int f = 0; f < 64; ++f) {
        float wx = Wx[(size_t)f * (4 * Uq) + col];
#pragma unroll
        for (int kk = 0; kk < 8; ++kk)
            acc[kk] = fmaf(WdL[kk][f], wx, acc[kk]);
    }
#pragma unroll
    for (int kk = 0; kk < 8; ++kk)
        Wtmp[(size_t)(k0 + kk) * (4 * Uq) + col] = acc[kk];
}

// bias2 = b + bd @ Wx. (r17-verified)
__global__ __launch_bounds__(256)
void bias2_kernel(const float* __restrict__ b, const float* __restrict__ bd,
                  const float* __restrict__ Wx, float* __restrict__ b2)
{
    const int col = (int)blockIdx.x * 256 + threadIdx.x;
    float acc = b[col];
    for (int f = 0; f < 64; ++f)
        acc = fmaf(bd[f], Wx[(size_t)f * (4 * Uq) + col], acc);
    b2[col] = acc;
}

// Pack Wcomb into decode B-frags (K=1024, 64 kc16). (r17-verified)
__global__ __launch_bounds__(256)
void pack_wc(const float* __restrict__ Wtmp, f16x8* __restrict__ BpD)
{
    long id = (long)blockIdx.x * 256 + threadIdx.x;   // 524288 slots
    int lane = (int)(id & 63);
    long rest = id >> 6;
    int kc16 = (int)(rest % NKC_D);
    int gcol = (int)(rest / NKC_D);                   // 0..127
    int col = (gcol >> 5) * Uq + (gcol & 31) * 32 + (lane & 31);
    int k0 = kc16 * 16 + (lane >> 5) * 8;
    f16x8 hv;
#pragma unroll
    for (int j = 0; j < 8; ++j)
        hv[j] = (_Float16)Wtmp[(size_t)(k0 + j) * (4 * Uq) + col];
    BpD[id] = hv;
}

// Transpose Wd [1024][64] fp32 -> WdT [64][1024] f16. Grid 256 x 256.
__global__ __launch_bounds__(256)
void pack_wdt(const float* __restrict__ Wd, _Float16* __restrict__ WdT)
{
    const int id = (int)blockIdx.x * 256 + threadIdx.x;   // 65536
    const int k = id >> 6;
    const int f = id & 63;
    WdT[(size_t)f * Uq + k] = (_Float16)Wd[(size_t)k * Fq + f];
}

// ---------------------------------------------------------------------------
// Fused LSTM step, FP16 MFMA, wide walls. (r16/r17-verified, unchanged)
// ---------------------------------------------------------------------------
#define STAGE_LOAD4(wl, bank) do {                                              \
    _Pragma("unroll")                                                           \
    for (int j_ = 0; j_ < 4; ++j_)                                              \
        ash[bank][j_] = *(const f16x8*)(hrow + ((wl) * 4 + j_) * 64);           \
} while (0)

#define STAGE_WRITE4(buf, bank) do {                                            \
    _Pragma("unroll")                                                           \
    for (int j_ = 0; j_ < 4; ++j_)                                              \
        As[buf][j_][smh][sslot] = ash[bank][j_];                                \
} while (0)

#define LOADB4(slot, wl) do {                                                   \
    _Pragma("unroll")                                                           \
    for (int j_ = 0; j_ < 4; ++j_) {                                            \
        Bh[slot][j_][0] = bpH0[(((wl) * 4 + j_) * 4 + kq) * 64];                \
        Bh[slot][j_][1] = bpH1[(((wl) * 4 + j_) * 4 + kq) * 64];                \
    }                                                                           \
} while (0)

#define COMPUTE4(buf, slot) do {                                                \
    _Pragma("unroll")                                                           \
    for (int j_ = 0; j_ < 4; ++j_) {                                            \
        f16x8 ah0_ = As[buf][j_][0][rdslot];                                    \
        f16x8 ah1_ = As[buf][j_][1][rdslot];                                    \
        __builtin_amdgcn_s_setprio(1);                                          \
        acc[0][0] = __builtin_amdgcn_mfma_f32_32x32x16_f16(ah0_, Bh[slot][j_][0], acc[0][0], 0, 0, 0); \
        acc[0][1] = __builtin_amdgcn_mfma_f32_32x32x16_f16(ah1_, Bh[slot][j_][0], acc[0][1], 0, 0, 0); \
        acc[1][0] = __builtin_amdgcn_mfma_f32_32x32x16_f16(ah0_, Bh[slot][j_][1], acc[1][0], 0, 0, 0); \
        acc[1][1] = __builtin_amdgcn_mfma_f32_32x32x16_f16(ah1_, Bh[slot][j_][1], acc[1][1], 0, 0, 0); \
        __builtin_amdgcn_s_setprio(0);                                          \
    }                                                                           \
} while (0)

__global__ __launch_bounds__(512, 2)
void lstm_step(const _Float16* __restrict__ h_in,   // [512][1024] f16
               const float* __restrict__ xsrc,      // fp32, 64 cols, stride xstride
               long xstride,
               const f16x8* __restrict__ BpH,
               const float* __restrict__ bias,      // [4096]
               _Float16* __restrict__ h_out,        // [512][1024] f16
               float* __restrict__ c_st,            // [512][1024] fp32 in/out
               int nkc, int use_x)
{
    __shared__ __align__(16) char smem[73728];
    f16x8 (*As)[4][2][256] = (f16x8 (*)[4][2][256])smem;        // [buf][chunk][mh][slot]
    f16x8 (*xbuf)[256] = (f16x8 (*)[256])(smem + 65536);        // [mh][slot]
    float (*zsd)[4][32][36] = (float (*)[4][32][36])smem;       // [kq][g][row][col]

    const int tid = threadIdx.x;
    const int l   = tid & 63;
    const int w   = tid >> 6;
    const int gp  = w & 1;
    const int kq  = w >> 1;
    const int bm  = (int)blockIdx.x >> 5;
    const int bu  = (int)blockIdx.x & 31;
    const int row0 = bm * 64;

    const int srow = tid >> 3;
    const int kg8  = tid & 7;
    const int smh  = srow >> 5;
    const int sr31 = srow & 31;
    const int sslot = sr31 * 8 + (kg8 ^ (sr31 & 7));

    const int rdslot = (l & 31) * 8 + ((kq * 2 + (l >> 5)) ^ (l & 7));

    const f16x8* bpH0 = BpH + ((size_t)((gp * 2 + 0) * 32 + bu) * nkc) * 64 + l;
    const f16x8* bpH1 = BpH + ((size_t)((gp * 2 + 1) * 32 + bu) * nkc) * 64 + l;
    const _Float16* hrow = h_in + (size_t)(row0 + srow) * Uq + kg8 * 8;
    const float*    xrow = xsrc + (size_t)(row0 + srow) * xstride + kg8 * 8;

    f32x16 acc[2][2];
#pragma unroll
    for (int i = 0; i < 16; ++i) {
        acc[0][0][i] = 0.0f; acc[0][1][i] = 0.0f;
        acc[1][0][i] = 0.0f; acc[1][1][i] = 0.0f;
    }

    f16x8 Bh[2][4][2];
    f16x8 Bx[2];
    f16x8 ash[2][4];

    // ---- prologue ----
    if (use_x) {
        f32x4 v0_ = *(const f32x4*)xrow;
        f32x4 v1_ = *(const f32x4*)(xrow + 4);
        f16x8 hv_;
#pragma unroll
        for (int j_ = 0; j_ < 4; ++j_) {
            hv_[j_]     = (_Float16)v0_[j_];
            hv_[4 + j_] = (_Float16)v1_[j_];
        }
        xbuf[smh][sslot] = hv_;
        Bx[0] = bpH0[(64 + kq) * 64];
        Bx[1] = bpH1[(64 + kq) * 64];
    }
    STAGE_LOAD4(0, 0);
    STAGE_LOAD4(1, 1);
    LOADB4(0, 0);
    STAGE_WRITE4(0, 0);
    BAR();

    LOADB4(1, 1);
    STAGE_LOAD4(2, 0);
    STAGE_WRITE4(1, 1);
    COMPUTE4(0, 0);
    BAR();
    LOADB4(0, 2);
    STAGE_LOAD4(3, 1);
    STAGE_WRITE4(0, 0);
    COMPUTE4(1, 1);
    BAR();
    LOADB4(1, 3);
    STAGE_WRITE4(1, 1);
    COMPUTE4(0, 0);
    BAR();
    COMPUTE4(1, 1);
    if (use_x) {
        f16x8 ah0_ = xbuf[0][rdslot];
        f16x8 ah1_ = xbuf[1][rdslot];
        acc[0][0] = __builtin_amdgcn_mfma_f32_32x32x16_f16(ah0_, Bx[0], acc[0][0], 0, 0, 0);
        acc[0][1] = __builtin_amdgcn_mfma_f32_32x32x16_f16(ah1_, Bx[0], acc[0][1], 0, 0, 0);
        acc[1][0] = __builtin_amdgcn_mfma_f32_32x32x16_f16(ah0_, Bx[1], acc[1][0], 0, 0, 0);
        acc[1][1] = __builtin_amdgcn_mfma_f32_32x32x16_f16(ah1_, Bx[1], acc[1][1], 0, 0, 0);
    }
    BAR();

    // ---- epilogue (r13/r16-verified) ----
#pragma unroll
    for (int mh = 0; mh < 2; ++mh) {
#pragma unroll
        for (int g2 = 0; g2 < 2; ++g2)
#pragma unroll
            for (int r = 0; r < 16; ++r) {
                int rowi = (r & 3) + 8 * (r >> 2) + 4 * (l >> 5);
                zsd[kq][gp * 2 + g2][rowi][l & 31] = acc[g2][mh][r];
            }
        BAR();
        {
            const int row = tid >> 4;
            const int uu  = (tid & 15) * 2;
            const int grow = row0 + mh * 32 + row;
            const int gu   = bu * 32 + uu;
            const size_t gidx = (size_t)grow * Uq + gu;
            float z[4][2];
#pragma unroll
            for (int g = 0; g < 4; ++g) {
#pragma unroll
                for (int j = 0; j < 2; ++j)
                    z[g][j] = zsd[0][g][row][uu + j] + zsd[1][g][row][uu + j]
                            + zsd[2][g][row][uu + j] + zsd[3][g][row][uu + j];
            }
            f32x2 cv = *(const f32x2*)(c_st + gidx);
            f16x2 hh;
#pragma unroll
            for (int j = 0; j < 2; ++j) {
                float vi = sigmoidf_(z[0][j] + bias[0 * Uq + gu + j]);
                float vf = sigmoidf_(z[1][j] + bias[1 * Uq + gu + j]);
                float vg = tanhf_  (z[2][j] + bias[2 * Uq + gu + j]);
                float vo = sigmoidf_(z[3][j] + bias[3 * Uq + gu + j]);
                float cn = vf * cv[j] + vi * vg;
                cv[j] = cn;
                hh[j] = (_Float16)(vo * tanhf_(cn));
            }
            *(f32x2*)(c_st + gidx) = cv;
            *(f16x2*)(h_out + gidx) = hh;
        }
        if (mh == 0) BAR();
    }
}

// ---------------------------------------------------------------------------
// Fallback per-step readout (r13-verified).
// ---------------------------------------------------------------------------
__global__ __launch_bounds__(256)
void readout(const _Float16* __restrict__ h, const float* __restrict__ Wd,
             const float* __restrict__ bd, float* __restrict__ p,
             float* __restrict__ out, int step)
{
    __shared__ float red[2][4][64];
    const int t = threadIdx.x;
    const int f = t & 63, kq = t >> 6;
    const int r0 = blockIdx.x * 2;
    float s0 = 0.0f, s1 = 0.0f;
    const _Float16* h0 = h + (size_t)r0 * Uq + kq * 256;
    const float* wp = Wd + (size_t)kq * 256 * Fq + f;
#pragma unroll 4
    for (int i = 0; i < 32; ++i) {
        f16x8 ah = *(const f16x8*)(h0 + i * 8);
        f16x8 bh = *(const f16x8*)(h0 + Uq + i * 8);
#pragma unroll
        for (int j = 0; j < 8; ++j) {
            float wv = wp[(size_t)(i * 8 + j) * Fq];
            s0 = fmaf((float)ah[j], wv, s0);
            s1 = fmaf((float)bh[j], wv, s1);
        }
    }
    red[0][kq][f] = s0;
    red[1][kq][f] = s1;
    __syncthreads();
    if (t < 128) {
        int rr = t >> 6, ff = t & 63;
        float s = red[rr][0][ff] + red[rr][1][ff] + red[rr][2][ff] + red[rr][3][ff] + bd[ff];
        p[(size_t)(r0 + rr) * Fq + ff] = s;
        out[((size_t)(r0 + rr) * OSTEPS + step) * Fq + ff] = s;
    }
}

// ---------------------------------------------------------------------------
// Batched readout v2: vectorized WdT (f16x8) rows + v_dot2_f32_f16.
// out[r,s,:] = h_s[r,:] @ Wd + bd. Grid 6144 = 24 slots x 256 (2 rows each).
// ---------------------------------------------------------------------------
__global__ __launch_bounds__(256)
void readout_all(const _Float16* __restrict__ slots, const _Float16* __restrict__ WdT,
                 const float* __restrict__ bd, float* __restrict__ out)
{
    __shared__ float red[2][4][64];
    const int t = threadIdx.x;
    const int f = t & 63, kq = t >> 6;
    const int s = (int)blockIdx.x >> 8;
    const int r0 = ((int)blockIdx.x & 255) * 2;
    const _Float16* h0 = slots + (size_t)s * SLOT + (size_t)r0 * Uq + kq * 256;
    const _Float16* wr = WdT + (size_t)f * Uq + kq * 256;
    float s0 = 0.0f, s1 = 0.0f;
#pragma unroll 4
    for (int i = 0; i < 32; ++i) {
        union { f16x8 v; f16x2 p[4]; } uw, ua, ub;
        uw.v = *(const f16x8*)(wr + i * 8);
        ua.v = *(const f16x8*)(h0 + i * 8);
        ub.v = *(const f16x8*)(h0 + Uq + i * 8);
#pragma unroll
        for (int j = 0; j < 4; ++j) {
#if __has_builtin(__builtin_amdgcn_fdot2)
            s0 = __builtin_amdgcn_fdot2(ua.p[j], uw.p[j], s0, false);
            s1 = __builtin_amdgcn_fdot2(ub.p[j], uw.p[j], s1, false);
#else
            s0 = fmaf((float)ua.p[j][0], (float)uw.p[j][0], s0);
            s0 = fmaf((float)ua.p[j][1], (float)uw.p[j][1], s0);
            s1 = fmaf((float)ub.p[j][0], (float)uw.p[j][0], s1);
            s1 = fmaf((float)ub.p[j][1], (float)uw.p[j][1], s1);
#endif
        }
    }
    red[0][kq][f] = s0;
    red[1][kq][f] = s1;
    __syncthreads();
    if (t < 128) {
        int rr = t >> 6, ff = t & 63;
        float sum = red[rr][0][ff] + red[rr][1][ff] + red[rr][2][ff] + red[rr][3][ff] + bd[ff];
        out[((size_t)(r0 + rr) * OSTEPS + s) * Fq + ff] = sum;
    }
}

__global__ void zero_ws(f32x4* __restrict__ a, int n) {
    int i = blockIdx.x * 256 + threadIdx.x;
    f32x4 z = {0.0f, 0.0f, 0.0f, 0.0f};
    if (i < n) a[i] = z;
}

extern "C" void kernel_launch(void* const* d_in, const int* in_sizes, int n_in,
                              void* d_out, int out_size, void* d_ws, size_t ws_size,
                              hipStream_t stream) {
    const float* inputs = (const float*)d_in[0];  // [512][128][64]
    const float* Wx     = (const float*)d_in[1];  // [64][4096]
    const float* Wh     = (const float*)d_in[2];  // [1024][4096]
    const float* b      = (const float*)d_in[3];  // [4096]
    const float* Wd     = (const float*)d_in[4];  // [1024][64]
    const float* bd     = (const float*)d_in[5];  // [64]
    float* out = (float*)d_out;
    char* ws = (char*)d_ws;

    const size_t off_slots = 2097152;
    const size_t off_Bw    = off_slots + 25ull * 1048576;
    const size_t off_Bd    = off_Bw + 8912896;
    const size_t off_b2    = off_Bd + 8388608;
    const size_t off_wdt   = off_b2 + 16384;
    const size_t need_fold = off_wdt + 131072;
    const int fold = (ws_size >= need_fold) ? 1 : 0;

    if (fold) {
        float*    c_st  = (float*)ws;
        _Float16* slots = (_Float16*)(ws + off_slots);
        f16x8*    Bw    = (f16x8*)(ws + off_Bw);
        f16x8*    Bd    = (f16x8*)(ws + off_Bd);
        float*    b2    = (float*)(ws + off_b2);
        _Float16* WdT   = (_Float16*)(ws + off_wdt);
        float*    Wtmp  = (float*)(ws + off_slots);      // aliases slots 0..15

        pack_w<<<2176, 256, 0, stream>>>(Wh, Wx, Bw);
        wcomb_kernel<<<2048, 256, 0, stream>>>(Wh, Wd, Wx, Wtmp);
        bias2_kernel<<<16, 256, 0, stream>>>(b, bd, Wx, b2);
        pack_wc<<<2048, 256, 0, stream>>>(Wtmp, Bd);
        pack_wdt<<<256, 256, 0, stream>>>(Wd, WdT);
        zero_ws<<<768, 256, 0, stream>>>((f32x4*)ws, 196608);   // c + slot0

        _Float16* aux = slots + 24 * SLOT;
        _Float16* hc = slots;
        _Float16* hn = aux;
        for (int t = 0; t < Tq; ++t) {
            lstm_step<<<256, 512, 0, stream>>>(hc, inputs + (size_t)t * Fq,
                                               (long)Tq * Fq, Bw, b, hn, c_st,
                                               NKC_W, 1);
            _Float16* tmp = hc; hc = hn; hn = tmp;
        }
        for (int s = 1; s < OSTEPS; ++s) {
            lstm_step<<<256, 512, 0, stream>>>(slots + (size_t)(s - 1) * SLOT,
                                               inputs, (long)Fq, Bd, b2,
                                               slots + (size_t)s * SLOT, c_st,
                                               NKC_D, 0);
        }
        readout_all<<<24 * 256, 256, 0, stream>>>(slots, WdT, bd, out);
    } else {
        // fallback = r16 layout/flow
        float* c_st = (float*)ws;
        _Float16* H0 = (_Float16*)(ws + 2097152);
        _Float16* H1 = H0 + SLOT;
        float* p = (float*)(H1 + SLOT);
        f16x8* Bw = (f16x8*)((char*)p + Bq * Fq * 4);

        pack_w<<<2176, 256, 0, stream>>>(Wh, Wx, Bw);
        zero_ws<<<768, 256, 0, stream>>>((f32x4*)ws, 196608);

        _Float16 *hc = H0, *hn = H1;
        for (int t = 0; t < Tq; ++t) {
            lstm_step<<<256, 512, 0, stream>>>(hc, inputs + (size_t)t * Fq,
                                               (long)Tq * Fq, Bw, b, hn, c_st,
                                               NKC_W, 1);
            _Float16* tmp = hc; hc = hn; hn = tmp;
        }
        readout<<<Bq / 2, 256, 0, stream>>>(hc, Wd, bd, p, out, 0);
        for (int s = 1; s < OSTEPS; ++s) {
            lstm_step<<<256, 512, 0, stream>>>(hc, p, (long)Fq, Bw, b, hn, c_st,
                                               NKC_W, 1);
            _Float16* tmp = hc; hc = hn; hn = tmp;
            readout<<<Bq / 2, 256, 0, stream>>>(hc, Wd, bd, p, out, s);
        }
    }
}

// Round 19
// 1660.821 us; speedup vs baseline: 1.0508x; 1.0508x over previous
//
#include <hip/hip_runtime.h>
#include <math.h>

#define Bq 512
#define Tq 128
#define Fq 64
#define Uq 1024
#define OSTEPS 24
#define NKC_W 68
#define NKC_D 64
#define SLOT ((size_t)Bq * Uq)   // f16 elements per h slot

typedef _Float16 f16x8 __attribute__((ext_vector_type(8)));
typedef _Float16 f16x2 __attribute__((ext_vector_type(2)));
typedef float f32x16 __attribute__((ext_vector_type(16)));
typedef float f32x4 __attribute__((ext_vector_type(4)));
typedef float f32x2 __attribute__((ext_vector_type(2)));

__device__ __forceinline__ float sigmoidf_(float x) {
    return 1.0f / (1.0f + __expf(-x));
}
__device__ __forceinline__ float tanhf_(float x) {
    return 2.0f / (1.0f + __expf(-2.0f * x)) - 1.0f;
}

#define BAR() do {                                             \
    asm volatile("s_waitcnt lgkmcnt(0)" ::: "memory");         \
    __builtin_amdgcn_s_barrier();                              \
} while (0)

// ---------------------------------------------------------------------------
// Pack Wh [1024][4096] + Wx [64][4096] into warmup B-frags (K=1088, 68 kc16).
// (r13/r16/r17-verified)
// ---------------------------------------------------------------------------
__global__ __launch_bounds__(256)
void pack_w(const float* __restrict__ Wh, const float* __restrict__ Wx,
            f16x8* __restrict__ BpH)
{
    long id = (long)blockIdx.x * 256 + threadIdx.x;   // 128*68*64 slots
    int lane = (int)(id & 63);
    long rest = id >> 6;
    int kc16 = (int)(rest % NKC_W);
    int gcol = (int)(rest / NKC_W);                   // 0..127
    int col = (gcol >> 5) * Uq + (gcol & 31) * 32 + (lane & 31);
    int k0 = kc16 * 16 + (lane >> 5) * 8;
    f16x8 hv;
#pragma unroll
    for (int j = 0; j < 8; ++j) {
        int k = k0 + j;
        float v = (k < Uq) ? Wh[(size_t)k * (4 * Uq) + col]
                           : Wx[(size_t)(k - Uq) * (4 * Uq) + col];
        hv[j] = (_Float16)v;
    }
    BpH[id] = hv;
}

// ---------------------------------------------------------------------------
// Wcomb = Wh + Wd @ Wx  (fp32). (r17-verified)
// ---------------------------------------------------------------------------
__global__ __launch_bounds__(256)
void wcomb_kernel(const float* __restrict__ Wh, const float* __restrict__ Wd,
                  const float* __restrict__ Wx, float* __restrict__ Wtmp)
{
    __shared__ float WdL[8][64];
    const int tid = threadIdx.x;
    const int kb = (int)blockIdx.x >> 4;     // 0..127
    const int cb = (int)blockIdx.x & 15;
    const int k0 = kb * 8;
    const int col = cb * 256 + tid;
    {
        int i0 = tid, i1 = tid + 256;
        WdL[i0 >> 6][i0 & 63] = Wd[(size_t)(k0 + (i0 >> 6)) * Fq + (i0 & 63)];
        WdL[i1 >> 6][i1 & 63] = Wd[(size_t)(k0 + (i1 >> 6)) * Fq + (i1 & 63)];
    }
    __syncthreads();
    float acc[8];
#pragma unroll
    for (int kk = 0; kk < 8; ++kk)
        acc[kk] = Wh[(size_t)(k0 + kk) * (4 * Uq) + col];
    for (int f = 0; f < 64; ++f) {
        float wx = Wx[(size_t)f * (4 * Uq) + col];
#pragma unroll
        for (int kk = 0; kk < 8; ++kk)
            acc[kk] = fmaf(WdL[kk][f], wx, acc[kk]);
    }
#pragma unroll
    for (int kk = 0; kk < 8; ++kk)
        Wtmp[(size_t)(k0 + kk) * (4 * Uq) + col] = acc[kk];
}

// bias2 = b + bd @ Wx. (r17-verified)
__global__ __launch_bounds__(256)
void bias2_kernel(const float* __restrict__ b, const float* __restrict__ bd,
                  const float* __restrict__ Wx, float* __restrict__ b2)
{
    const int col = (int)blockIdx.x * 256 + threadIdx.x;
    float acc = b[col];
    for (int f = 0; f < 64; ++f)
        acc = fmaf(bd[f], Wx[(size_t)f * (4 * Uq) + col], acc);
    b2[col] = acc;
}

// Pack Wcomb into decode B-frags (K=1024, 64 kc16). (r17-verified)
__global__ __launch_bounds__(256)
void pack_wc(const float* __restrict__ Wtmp, f16x8* __restrict__ BpD)
{
    long id = (long)blockIdx.x * 256 + threadIdx.x;   // 524288 slots
    int lane = (int)(id & 63);
    long rest = id >> 6;
    int kc16 = (int)(rest % NKC_D);
    int gcol = (int)(rest / NKC_D);                   // 0..127
    int col = (gcol >> 5) * Uq + (gcol & 31) * 32 + (lane & 31);
    int k0 = kc16 * 16 + (lane >> 5) * 8;
    f16x8 hv;
#pragma unroll
    for (int j = 0; j < 8; ++j)
        hv[j] = (_Float16)Wtmp[(size_t)(k0 + j) * (4 * Uq) + col];
    BpD[id] = hv;
}

// ---------------------------------------------------------------------------
// Fused LSTM step, FP16 MFMA, wide walls. (r16/r17-verified, unchanged)
// ---------------------------------------------------------------------------
#define STAGE_LOAD4(wl, bank) do {                                              \
    _Pragma("unroll")                                                           \
    for (int j_ = 0; j_ < 4; ++j_)                                              \
        ash[bank][j_] = *(const f16x8*)(hrow + ((wl) * 4 + j_) * 64);           \
} while (0)

#define STAGE_WRITE4(buf, bank) do {                                            \
    _Pragma("unroll")                                                           \
    for (int j_ = 0; j_ < 4; ++j_)                                              \
        As[buf][j_][smh][sslot] = ash[bank][j_];                                \
} while (0)

#define LOADB4(slot, wl) do {                                                   \
    _Pragma("unroll")                                                           \
    for (int j_ = 0; j_ < 4; ++j_) {                                            \
        Bh[slot][j_][0] = bpH0[(((wl) * 4 + j_) * 4 + kq) * 64];                \
        Bh[slot][j_][1] = bpH1[(((wl) * 4 + j_) * 4 + kq) * 64];                \
    }                                                                           \
} while (0)

#define COMPUTE4(buf, slot) do {                                                \
    _Pragma("unroll")                                                           \
    for (int j_ = 0; j_ < 4; ++j_) {                                            \
        f16x8 ah0_ = As[buf][j_][0][rdslot];                                    \
        f16x8 ah1_ = As[buf][j_][1][rdslot];                                    \
        __builtin_amdgcn_s_setprio(1);                                          \
        acc[0][0] = __builtin_amdgcn_mfma_f32_32x32x16_f16(ah0_, Bh[slot][j_][0], acc[0][0], 0, 0, 0); \
        acc[0][1] = __builtin_amdgcn_mfma_f32_32x32x16_f16(ah1_, Bh[slot][j_][0], acc[0][1], 0, 0, 0); \
        acc[1][0] = __builtin_amdgcn_mfma_f32_32x32x16_f16(ah0_, Bh[slot][j_][1], acc[1][0], 0, 0, 0); \
        acc[1][1] = __builtin_amdgcn_mfma_f32_32x32x16_f16(ah1_, Bh[slot][j_][1], acc[1][1], 0, 0, 0); \
        __builtin_amdgcn_s_setprio(0);                                          \
    }                                                                           \
} while (0)

__global__ __launch_bounds__(512, 2)
void lstm_step(const _Float16* __restrict__ h_in,   // [512][1024] f16
               const float* __restrict__ xsrc,      // fp32, 64 cols, stride xstride
               long xstride,
               const f16x8* __restrict__ BpH,
               const float* __restrict__ bias,      // [4096]
               _Float16* __restrict__ h_out,        // [512][1024] f16
               float* __restrict__ c_st,            // [512][1024] fp32 in/out
               int nkc, int use_x)
{
    __shared__ __align__(16) char smem[73728];
    f16x8 (*As)[4][2][256] = (f16x8 (*)[4][2][256])smem;        // [buf][chunk][mh][slot]
    f16x8 (*xbuf)[256] = (f16x8 (*)[256])(smem + 65536);        // [mh][slot]
    float (*zsd)[4][32][36] = (float (*)[4][32][36])smem;       // [kq][g][row][col]

    const int tid = threadIdx.x;
    const int l   = tid & 63;
    const int w   = tid >> 6;
    const int gp  = w & 1;
    const int kq  = w >> 1;
    const int bm  = (int)blockIdx.x >> 5;
    const int bu  = (int)blockIdx.x & 31;
    const int row0 = bm * 64;

    const int srow = tid >> 3;
    const int kg8  = tid & 7;
    const int smh  = srow >> 5;
    const int sr31 = srow & 31;
    const int sslot = sr31 * 8 + (kg8 ^ (sr31 & 7));

    const int rdslot = (l & 31) * 8 + ((kq * 2 + (l >> 5)) ^ (l & 7));

    const f16x8* bpH0 = BpH + ((size_t)((gp * 2 + 0) * 32 + bu) * nkc) * 64 + l;
    const f16x8* bpH1 = BpH + ((size_t)((gp * 2 + 1) * 32 + bu) * nkc) * 64 + l;
    const _Float16* hrow = h_in + (size_t)(row0 + srow) * Uq + kg8 * 8;
    const float*    xrow = xsrc + (size_t)(row0 + srow) * xstride + kg8 * 8;

    f32x16 acc[2][2];
#pragma unroll
    for (int i = 0; i < 16; ++i) {
        acc[0][0][i] = 0.0f; acc[0][1][i] = 0.0f;
        acc[1][0][i] = 0.0f; acc[1][1][i] = 0.0f;
    }

    f16x8 Bh[2][4][2];
    f16x8 Bx[2];
    f16x8 ash[2][4];

    // ---- prologue ----
    if (use_x) {
        f32x4 v0_ = *(const f32x4*)xrow;
        f32x4 v1_ = *(const f32x4*)(xrow + 4);
        f16x8 hv_;
#pragma unroll
        for (int j_ = 0; j_ < 4; ++j_) {
            hv_[j_]     = (_Float16)v0_[j_];
            hv_[4 + j_] = (_Float16)v1_[j_];
        }
        xbuf[smh][sslot] = hv_;
        Bx[0] = bpH0[(64 + kq) * 64];
        Bx[1] = bpH1[(64 + kq) * 64];
    }
    STAGE_LOAD4(0, 0);
    STAGE_LOAD4(1, 1);
    LOADB4(0, 0);
    STAGE_WRITE4(0, 0);
    BAR();

    LOADB4(1, 1);
    STAGE_LOAD4(2, 0);
    STAGE_WRITE4(1, 1);
    COMPUTE4(0, 0);
    BAR();
    LOADB4(0, 2);
    STAGE_LOAD4(3, 1);
    STAGE_WRITE4(0, 0);
    COMPUTE4(1, 1);
    BAR();
    LOADB4(1, 3);
    STAGE_WRITE4(1, 1);
    COMPUTE4(0, 0);
    BAR();
    COMPUTE4(1, 1);
    if (use_x) {
        f16x8 ah0_ = xbuf[0][rdslot];
        f16x8 ah1_ = xbuf[1][rdslot];
        acc[0][0] = __builtin_amdgcn_mfma_f32_32x32x16_f16(ah0_, Bx[0], acc[0][0], 0, 0, 0);
        acc[0][1] = __builtin_amdgcn_mfma_f32_32x32x16_f16(ah1_, Bx[0], acc[0][1], 0, 0, 0);
        acc[1][0] = __builtin_amdgcn_mfma_f32_32x32x16_f16(ah0_, Bx[1], acc[1][0], 0, 0, 0);
        acc[1][1] = __builtin_amdgcn_mfma_f32_32x32x16_f16(ah1_, Bx[1], acc[1][1], 0, 0, 0);
    }
    BAR();

    // ---- epilogue (r13/r16-verified) ----
#pragma unroll
    for (int mh = 0; mh < 2; ++mh) {
#pragma unroll
        for (int g2 = 0; g2 < 2; ++g2)
#pragma unroll
            for (int r = 0; r < 16; ++r) {
                int rowi = (r & 3) + 8 * (r >> 2) + 4 * (l >> 5);
                zsd[kq][gp * 2 + g2][rowi][l & 31] = acc[g2][mh][r];
            }
        BAR();
        {
            const int row = tid >> 4;
            const int uu  = (tid & 15) * 2;
            const int grow = row0 + mh * 32 + row;
            const int gu   = bu * 32 + uu;
            const size_t gidx = (size_t)grow * Uq + gu;
            float z[4][2];
#pragma unroll
            for (int g = 0; g < 4; ++g) {
#pragma unroll
                for (int j = 0; j < 2; ++j)
                    z[g][j] = zsd[0][g][row][uu + j] + zsd[1][g][row][uu + j]
                            + zsd[2][g][row][uu + j] + zsd[3][g][row][uu + j];
            }
            f32x2 cv = *(const f32x2*)(c_st + gidx);
            f16x2 hh;
#pragma unroll
            for (int j = 0; j < 2; ++j) {
                float vi = sigmoidf_(z[0][j] + bias[0 * Uq + gu + j]);
                float vf = sigmoidf_(z[1][j] + bias[1 * Uq + gu + j]);
                float vg = tanhf_  (z[2][j] + bias[2 * Uq + gu + j]);
                float vo = sigmoidf_(z[3][j] + bias[3 * Uq + gu + j]);
                float cn = vf * cv[j] + vi * vg;
                cv[j] = cn;
                hh[j] = (_Float16)(vo * tanhf_(cn));
            }
            *(f32x2*)(c_st + gidx) = cv;
            *(f16x2*)(h_out + gidx) = hh;
        }
        if (mh == 0) BAR();
    }
}

// ---------------------------------------------------------------------------
// Fallback per-step readout (r13-verified).
// ---------------------------------------------------------------------------
__global__ __launch_bounds__(256)
void readout(const _Float16* __restrict__ h, const float* __restrict__ Wd,
             const float* __restrict__ bd, float* __restrict__ p,
             float* __restrict__ out, int step)
{
    __shared__ float red[2][4][64];
    const int t = threadIdx.x;
    const int f = t & 63, kq = t >> 6;
    const int r0 = blockIdx.x * 2;
    float s0 = 0.0f, s1 = 0.0f;
    const _Float16* h0 = h + (size_t)r0 * Uq + kq * 256;
    const float* wp = Wd + (size_t)kq * 256 * Fq + f;
#pragma unroll 4
    for (int i = 0; i < 32; ++i) {
        f16x8 ah = *(const f16x8*)(h0 + i * 8);
        f16x8 bh = *(const f16x8*)(h0 + Uq + i * 8);
#pragma unroll
        for (int j = 0; j < 8; ++j) {
            float wv = wp[(size_t)(i * 8 + j) * Fq];
            s0 = fmaf((float)ah[j], wv, s0);
            s1 = fmaf((float)bh[j], wv, s1);
        }
    }
    red[0][kq][f] = s0;
    red[1][kq][f] = s1;
    __syncthreads();
    if (t < 128) {
        int rr = t >> 6, ff = t & 63;
        float s = red[rr][0][ff] + red[rr][1][ff] + red[rr][2][ff] + red[rr][3][ff] + bd[ff];
        p[(size_t)(r0 + rr) * Fq + ff] = s;
        out[((size_t)(r0 + rr) * OSTEPS + step) * Fq + ff] = s;
    }
}

// ---------------------------------------------------------------------------
// Batched readout v3: coalesced fp32 Wd (r17 pattern) amortized over 8 rows
// per block. Grid 1536 = 24 slots x 64 blocks.
// ---------------------------------------------------------------------------
__global__ __launch_bounds__(256)
void readout_all(const _Float16* __restrict__ slots, const float* __restrict__ Wd,
                 const float* __restrict__ bd, float* __restrict__ out)
{
    __shared__ float red[8][4][64];   // 8 KB
    const int t = threadIdx.x;
    const int f = t & 63, kq = t >> 6;
    const int s  = (int)blockIdx.x >> 6;          // slot 0..23
    const int r0 = ((int)blockIdx.x & 63) * 8;    // row base
    const _Float16* h0 = slots + (size_t)s * SLOT + (size_t)r0 * Uq + kq * 256;
    const float* wp = Wd + (size_t)kq * 256 * Fq + f;
    float acc[8];
#pragma unroll
    for (int r = 0; r < 8; ++r) acc[r] = 0.0f;
#pragma unroll 2
    for (int i = 0; i < 32; ++i) {
        f16x8 hv[8];
#pragma unroll
        for (int r = 0; r < 8; ++r)
            hv[r] = *(const f16x8*)(h0 + (size_t)r * Uq + i * 8);
#pragma unroll
        for (int j = 0; j < 8; ++j) {
            float wv = wp[(size_t)(i * 8 + j) * Fq];
#pragma unroll
            for (int r = 0; r < 8; ++r)
                acc[r] = fmaf((float)hv[r][j], wv, acc[r]);
        }
    }
#pragma unroll
    for (int r = 0; r < 8; ++r) red[r][kq][f] = acc[r];
    __syncthreads();
#pragma unroll
    for (int q = 0; q < 2; ++q) {
        const int idx = t + q * 256;
        const int rr = idx >> 6, ff = idx & 63;
        float sum = red[rr][0][ff] + red[rr][1][ff] + red[rr][2][ff]
                  + red[rr][3][ff] + bd[ff];
        out[((size_t)(r0 + rr) * OSTEPS + s) * Fq + ff] = sum;
    }
}

__global__ void zero_ws(f32x4* __restrict__ a, int n) {
    int i = blockIdx.x * 256 + threadIdx.x;
    f32x4 z = {0.0f, 0.0f, 0.0f, 0.0f};
    if (i < n) a[i] = z;
}

extern "C" void kernel_launch(void* const* d_in, const int* in_sizes, int n_in,
                              void* d_out, int out_size, void* d_ws, size_t ws_size,
                              hipStream_t stream) {
    const float* inputs = (const float*)d_in[0];  // [512][128][64]
    const float* Wx     = (const float*)d_in[1];  // [64][4096]
    const float* Wh     = (const float*)d_in[2];  // [1024][4096]
    const float* b      = (const float*)d_in[3];  // [4096]
    const float* Wd     = (const float*)d_in[4];  // [1024][64]
    const float* bd     = (const float*)d_in[5];  // [64]
    float* out = (float*)d_out;
    char* ws = (char*)d_ws;

    const size_t off_slots = 2097152;
    const size_t off_Bw    = off_slots + 25ull * 1048576;
    const size_t off_Bd    = off_Bw + 8912896;
    const size_t off_b2    = off_Bd + 8388608;
    const size_t need_fold = off_b2 + 16384;
    const int fold = (ws_size >= need_fold) ? 1 : 0;

    if (fold) {
        float*    c_st  = (float*)ws;
        _Float16* slots = (_Float16*)(ws + off_slots);
        f16x8*    Bw    = (f16x8*)(ws + off_Bw);
        f16x8*    Bd    = (f16x8*)(ws + off_Bd);
        float*    b2    = (float*)(ws + off_b2);
        float*    Wtmp  = (float*)(ws + off_slots);      // aliases slots 0..15

        pack_w<<<2176, 256, 0, stream>>>(Wh, Wx, Bw);
        wcomb_kernel<<<2048, 256, 0, stream>>>(Wh, Wd, Wx, Wtmp);
        bias2_kernel<<<16, 256, 0, stream>>>(b, bd, Wx, b2);
        pack_wc<<<2048, 256, 0, stream>>>(Wtmp, Bd);
        zero_ws<<<768, 256, 0, stream>>>((f32x4*)ws, 196608);   // c + slot0

        _Float16* aux = slots + 24 * SLOT;
        _Float16* hc = slots;
        _Float16* hn = aux;
        for (int t = 0; t < Tq; ++t) {
            lstm_step<<<256, 512, 0, stream>>>(hc, inputs + (size_t)t * Fq,
                                               (long)Tq * Fq, Bw, b, hn, c_st,
                                               NKC_W, 1);
            _Float16* tmp = hc; hc = hn; hn = tmp;
        }
        for (int s = 1; s < OSTEPS; ++s) {
            lstm_step<<<256, 512, 0, stream>>>(slots + (size_t)(s - 1) * SLOT,
                                               inputs, (long)Fq, Bd, b2,
                                               slots + (size_t)s * SLOT, c_st,
                                               NKC_D, 0);
        }
        readout_all<<<24 * 64, 256, 0, stream>>>(slots, Wd, bd, out);
    } else {
        // fallback = r16 layout/flow
        float* c_st = (float*)ws;
        _Float16* H0 = (_Float16*)(ws + 2097152);
        _Float16* H1 = H0 + SLOT;
        float* p = (float*)(H1 + SLOT);
        f16x8* Bw = (f16x8*)((char*)p + Bq * Fq * 4);

        pack_w<<<2176, 256, 0, stream>>>(Wh, Wx, Bw);
        zero_ws<<<768, 256, 0, stream>>>((f32x4*)ws, 196608);

        _Float16 *hc = H0, *hn = H1;
        for (int t = 0; t < Tq; ++t) {
            lstm_step<<<256, 512, 0, stream>>>(hc, inputs + (size_t)t * Fq,
                                               (long)Tq * Fq, Bw, b, hn, c_st,
                                               NKC_W, 1);
            _Float16* tmp = hc; hc = hn; hn = tmp;
        }
        readout<<<Bq / 2, 256, 0, stream>>>(hc, Wd, bd, p, out, 0);
        for (int s = 1; s < OSTEPS; ++s) {
            lstm_step<<<256, 512, 0, stream>>>(hc, p, (long)Fq, Bw, b, hn, c_st,
                                               NKC_W, 1);
            _Float16* tmp = hc; hc = hn; hn = tmp;
            readout<<<Bq / 2, 256, 0, stream>>>(hc, Wd, bd, p, out, s);
        }
    }
}